// Round 8
// baseline (161.126 us; speedup 1.0000x reference)
//
#include <hip/hip_runtime.h>
#include <hip/hip_bf16.h>

typedef __attribute__((ext_vector_type(8))) short bf16x8;
typedef __attribute__((ext_vector_type(4))) float f32x4;

#define B_N   16384
#define INP_N 4096
#define M_N   100
#define K_N   32
#define HID_N 32
#define OUT_W 10

// ---------------- workspace layout (bytes) ----------------
#define WS_TW1 0u         // bf16[100][32][32]   tW1[m][h][k]      204800
#define WS_TW2 204800u    // bf16[100][16][32]   tW2[m][o(pad)][k-slot] 102400
#define WS_TB1 307200u    // f32 [100][32]       tb1               12800
#define WS_TB2 320000u    // f32 [100][16]       tb2               6400
#define WS_COL 326400u    // u16 [100][32]       idx cols packed   6400
// total 332800 B

// ---------------- kernel-2 LDS layout (bytes) ----------------
#define ROWB   8208                  // bf16 row: 8192 B data + 16 B pad (4-bank rotate/row)
#define BUFB   (16 * ROWB)           // 131328: ONE 16-row tile buffer
#define REDOFF BUFB                  // per-wave out partials
#define REDSTR 656                   // 164 dwords (16B aligned, rotates 4 banks/wave)
#define COLOFF (REDOFF + 16 * REDSTR)   // 141824: u16[100][32] col table
#define TB1OFF (COLOFF + 6400)          // 148224: f32[100][32] tb1
#define TB2OFF (TB1OFF + 12800)         // 161024: f32[10] summed tb2
#define LDS_SZ (TB2OFF + 64)            // 161088  (<= 163840)

__device__ __forceinline__ unsigned int pkbf(float a, float b) {
    __hip_bfloat162 h2 = __float22bfloat162_rn(make_float2(a, b));
    unsigned int r;
    __builtin_memcpy(&r, &h2, 4);
    return r;
}

// =====================================================================
// Kernel 1: fused hypernetwork.  One block per m, 512 threads.
// (byte-identical to rounds 5-7; launched 3x this round as an
//  attribution probe: dur = 3H + M, H = (dur - 98.0)/2)
// =====================================================================
__global__ __launch_bounds__(512) void hyper_kernel(
    const int* __restrict__ idx,
    const float* __restrict__ Wi, const float* __restrict__ bi,
    const float* __restrict__ W1, const float* __restrict__ b1,
    const float* __restrict__ W2, const float* __restrict__ b2,
    const float* __restrict__ Wo, const float* __restrict__ bo,
    char* __restrict__ ws)
{
    __shared__ int   s_idx[K_N];
    __shared__ float s_h0[64];
    __shared__ float s_h1[256];
    __shared__ float s_h2[128];
    const int m = blockIdx.x;
    const int t = threadIdx.x;

    __hip_bfloat16* tW1bf = (__hip_bfloat16*)(ws + WS_TW1);
    __hip_bfloat16* tW2bf = (__hip_bfloat16*)(ws + WS_TW2);
    float* tb1f = (float*)(ws + WS_TB1);
    float* tb2f = (float*)(ws + WS_TB2);
    unsigned short* colb = (unsigned short*)(ws + WS_COL);

    if (t < K_N) {
        int c = idx[m * K_N + t];
        s_idx[t] = c;
        colb[m * K_N + t] = (unsigned short)c;
    }
    __syncthreads();

    if (t < 64) {
        float s = bi[t];
        const float* wr = Wi + t * INP_N;
        int prev = -1;
        for (int k = 0; k < K_N; ++k) {
            int c = s_idx[k];
            if (c != prev) s += wr[c];
            prev = c;
        }
        s_h0[t] = fmaxf(s, 0.f);
    }
    __syncthreads();

    if (t < 256) {
        float4 a = {0.f, 0.f, 0.f, 0.f};
        const float4* wr = (const float4*)(W1 + t * 64);
        const float4* h0v = (const float4*)s_h0;
        #pragma unroll
        for (int i = 0; i < 16; ++i) {
            float4 w4 = wr[i], a4 = h0v[i];
            a.x += w4.x * a4.x; a.y += w4.y * a4.y;
            a.z += w4.z * a4.z; a.w += w4.w * a4.w;
        }
        s_h1[t] = fmaxf(b1[t] + (a.x + a.y) + (a.z + a.w), 0.f);
    }
    __syncthreads();

    if (t < 128) {
        float4 a = {0.f, 0.f, 0.f, 0.f};
        const float4* wr = (const float4*)(W2 + t * 256);
        const float4* h1v = (const float4*)s_h1;
        #pragma unroll
        for (int i = 0; i < 64; ++i) {
            float4 w4 = wr[i], a4 = h1v[i];
            a.x += w4.x * a4.x; a.y += w4.y * a4.y;
            a.z += w4.z * a4.z; a.w += w4.w * a4.w;
        }
        s_h2[t] = fmaxf(b2[t] + (a.x + a.y) + (a.z + a.w), 0.f);
    }
    __syncthreads();

    for (int o = t; o < 1386; o += 512) {
        float4 a = {0.f, 0.f, 0.f, 0.f};
        const float4* wr = (const float4*)(Wo + o * 128);
        const float4* h2v = (const float4*)s_h2;
        #pragma unroll
        for (int i = 0; i < 32; ++i) {
            float4 w4 = wr[i], a4 = h2v[i];
            a.x += w4.x * a4.x; a.y += w4.y * a4.y;
            a.z += w4.z * a4.z; a.w += w4.w * a4.w;
        }
        float s = bo[o] + (a.x + a.y) + (a.z + a.w);
        if (o < 1024) {
            tW1bf[m * 1024 + o] = __float2bfloat16(s);
        } else if (o < 1056) {
            tb1f[m * 32 + (o - 1024)] = s;
        } else if (o < 1376) {
            // k-slot permuted store (see main_kernel MFMA2)
            int i2 = o - 1056;
            int oo = i2 >> 5, h = i2 & 31;
            int sl = (((h & 15) >> 2) << 3) + (h & 3) + ((h >> 4) << 2);
            tW2bf[m * 512 + oo * 32 + sl] = __float2bfloat16(s);
        } else {
            tb2f[m * 16 + (o - 1376)] = s;
        }
    }
    if (t < 192) tW2bf[m * 512 + 320 + t] = __float2bfloat16(0.f);
}

// =====================================================================
// Kernel 2: main loop -- byte-exact round-5 version (best, 98.0 us).
// 256 blocks x 1024 thr (16 waves); 16-row tiles; half0 of the next
// tile prefetched before the m-loop, half1 loaded in the write phase.
// =====================================================================
__global__ __launch_bounds__(1024) void main_kernel(
    const float* __restrict__ data,
    const char* __restrict__ ws,
    float* __restrict__ out)
{
    extern __shared__ char smem[];
    const int tid  = threadIdx.x;
    const int lane = tid & 63;
    const int wave = tid >> 6;       // 0..15 ; wave w stages row w of each tile
    const int kg   = lane >> 4;      // 0..3  (MFMA k-group)
    const int ln15 = lane & 15;

    unsigned int* s_col = (unsigned int*)(smem + COLOFF);
    float* s_tb1 = (float*)(smem + TB1OFF);
    float* tb2s  = (float*)(smem + TB2OFF);

    // ---- small tables -> LDS ----
    {
        const unsigned int* colg = (const unsigned int*)(ws + WS_COL);
        for (int i = tid; i < 1600; i += 1024) s_col[i] = colg[i];
        const float* tb1g = (const float*)(ws + WS_TB1);
        for (int i = tid; i < 3200; i += 1024) s_tb1[i] = tb1g[i];
        if (tid < OUT_W) {
            const float* tb2f = (const float*)(ws + WS_TB2);
            float s = 0.f;
            for (int mm = 0; mm < M_N; ++mm) s += tb2f[mm * 16 + tid];
            tb2s[tid] = s;
        }
    }

    const int row0 = blockIdx.x * 64;         // 4 tiles x 16 rows
    const int mlo = (wave * M_N) >> 4;
    const int mhi = ((wave + 1) * M_N) >> 4;

    float4 v[8];                              // staging regs (one half-row)

    // ---- prologue: stage tile0 fully (both halves) ----
    {
        const float* rp = data + (size_t)(row0 + wave) * INP_N;
        char* bp = smem + wave * ROWB;
        #pragma unroll
        for (int half = 0; half < 2; ++half) {
            #pragma unroll
            for (int j = 0; j < 4; ++j) {
                v[2 * j]     = *(const float4*)(rp + half * 2048 + j * 512 + lane * 8);
                v[2 * j + 1] = *(const float4*)(rp + half * 2048 + j * 512 + lane * 8 + 4);
            }
            #pragma unroll
            for (int j = 0; j < 4; ++j) {
                uint4 pk;
                pk.x = pkbf(v[2 * j].x,     v[2 * j].y);
                pk.y = pkbf(v[2 * j].z,     v[2 * j].w);
                pk.z = pkbf(v[2 * j + 1].x, v[2 * j + 1].y);
                pk.w = pkbf(v[2 * j + 1].z, v[2 * j + 1].w);
                *(uint4*)(bp + half * 4096 + j * 1024 + lane * 16) = pk;
            }
        }
    }
    __syncthreads();

    for (int ti = 0; ti < 4; ++ti) {
        // early-issue next tile half0 (HBM hides under m-loop)
        if (ti < 3) {
            const float* rp = data + (size_t)(row0 + (ti + 1) * 16 + wave) * INP_N;
            #pragma unroll
            for (int j = 0; j < 4; ++j) {
                v[2 * j]     = *(const float4*)(rp + j * 512 + lane * 8);
                v[2 * j + 1] = *(const float4*)(rp + j * 512 + lane * 8 + 4);
            }
        }

        // ---- m-loop on current tile (16 real rows) ----
        const char* gbase = smem + ln15 * ROWB;
        f32x4 acc = {0.f, 0.f, 0.f, 0.f};

        // prefetch first column word
        uint4 cw = *(const uint4*)((const char*)s_col + mlo * 64 + kg * 16);

        for (int m = mlo; m < mhi; ++m) {
            // prefetch next m's column word (dep chain head)
            const int mn = (m + 1 < M_N) ? (m + 1) : m;
            const uint4 cwn = *(const uint4*)((const char*)s_col + mn * 64 + kg * 16);

            // B-frag (md): md[b=ln15][k=kg*8+j] gathered from staged bf16 row
            unsigned short u0 = *(const unsigned short*)(gbase + 2 * (cw.x & 0xFFFFu));
            unsigned short u1 = *(const unsigned short*)(gbase + 2 * (cw.x >> 16));
            unsigned short u2 = *(const unsigned short*)(gbase + 2 * (cw.y & 0xFFFFu));
            unsigned short u3 = *(const unsigned short*)(gbase + 2 * (cw.y >> 16));
            unsigned short u4 = *(const unsigned short*)(gbase + 2 * (cw.z & 0xFFFFu));
            unsigned short u5 = *(const unsigned short*)(gbase + 2 * (cw.z >> 16));
            unsigned short u6 = *(const unsigned short*)(gbase + 2 * (cw.w & 0xFFFFu));
            unsigned short u7 = *(const unsigned short*)(gbase + 2 * (cw.w >> 16));
            union { unsigned int ui[4]; bf16x8 v8; } af;
            af.ui[0] = (unsigned int)u0 | ((unsigned int)u1 << 16);
            af.ui[1] = (unsigned int)u2 | ((unsigned int)u3 << 16);
            af.ui[2] = (unsigned int)u4 | ((unsigned int)u5 << 16);
            af.ui[3] = (unsigned int)u6 | ((unsigned int)u7 << 16);

            // A-frags: tW1 rows h=ln15 / h=ln15+16; tW2 rows o=ln15 (slot-permuted)
            const bf16x8 w1a = *(const bf16x8*)(ws + WS_TW1 + m * 2048 + ln15 * 64 + kg * 16);
            const bf16x8 w1b = *(const bf16x8*)(ws + WS_TW1 + m * 2048 + 1024 + ln15 * 64 + kg * 16);
            const bf16x8 w2f = *(const bf16x8*)(ws + WS_TW2 + m * 1024 + ln15 * 64 + kg * 16);
            const float4 bq0 = *(const float4*)(s_tb1 + m * 32 + kg * 4);
            const float4 bq1 = *(const float4*)(s_tb1 + m * 32 + 16 + kg * 4);

            // MFMA1: C[h][b] = W1 x md  (bias tb1[h] as C-in; h = kg*4+r)
            f32x4 c0 = {bq0.x, bq0.y, bq0.z, bq0.w};
            f32x4 c1 = {bq1.x, bq1.y, bq1.z, bq1.w};
            c0 = __builtin_amdgcn_mfma_f32_16x16x32_bf16(w1a, af.v8, c0, 0, 0, 0);
            c1 = __builtin_amdgcn_mfma_f32_16x16x32_bf16(w1b, af.v8, c1, 0, 0, 0);

            // relu + pack: lane(b,kg) holds exactly its MFMA2 B-frag k-slots
            // (k=kg*8+j <-> h = 4kg + (j&3) + (j>=4 ? 16 : 0), matching tW2 store)
            #pragma unroll
            for (int r = 0; r < 4; ++r) { c0[r] = fmaxf(c0[r], 0.f); c1[r] = fmaxf(c1[r], 0.f); }
            union { unsigned int ui[4]; bf16x8 v8; } bfr;
            bfr.ui[0] = pkbf(c0[0], c0[1]);
            bfr.ui[1] = pkbf(c0[2], c0[3]);
            bfr.ui[2] = pkbf(c1[0], c1[1]);
            bfr.ui[3] = pkbf(c1[2], c1[3]);

            // MFMA2: acc[o][b] += tW2[o][.] x th[.][b]
            acc = __builtin_amdgcn_mfma_f32_16x16x32_bf16(w2f, bfr.v8, acc, 0, 0, 0);

            cw = cwn;
        }

        // per-wave partials: acc row o=kg*4+r, col b=ln15 (all 16 b real)
        {
            float* red = (float*)(smem + REDOFF + wave * REDSTR);
            #pragma unroll
            for (int r = 0; r < 4; ++r) {
                int o = kg * 4 + r;
                if (o < OUT_W) red[o * 16 + ln15] = acc[r];
            }
        }
        __syncthreads();

        // reduce 16 waves + tb2 + mean (160 threads) -- overlaps with the
        // register->LDS conversion below on the other threads
        if (tid < 160) {
            const int o = tid >> 4, b = tid & 15;
            float s = tb2s[o];
            #pragma unroll
            for (int w = 0; w < 16; ++w)
                s += *(const float*)(smem + REDOFF + w * REDSTR + tid * 4);
            out[(size_t)(row0 + ti * 16 + b) * OUT_W + o] = s * 0.01f;
        }

        // write phase: half0 from regs, then load+write half1
        if (ti < 3) {
            char* bp = smem + wave * ROWB;
            #pragma unroll
            for (int j = 0; j < 4; ++j) {
                uint4 pk;
                pk.x = pkbf(v[2 * j].x,     v[2 * j].y);
                pk.y = pkbf(v[2 * j].z,     v[2 * j].w);
                pk.z = pkbf(v[2 * j + 1].x, v[2 * j + 1].y);
                pk.w = pkbf(v[2 * j + 1].z, v[2 * j + 1].w);
                *(uint4*)(bp + j * 1024 + lane * 16) = pk;
            }
            const float* rp = data + (size_t)(row0 + (ti + 1) * 16 + wave) * INP_N + 2048;
            #pragma unroll
            for (int j = 0; j < 4; ++j) {
                v[2 * j]     = *(const float4*)(rp + j * 512 + lane * 8);
                v[2 * j + 1] = *(const float4*)(rp + j * 512 + lane * 8 + 4);
            }
            #pragma unroll
            for (int j = 0; j < 4; ++j) {
                uint4 pk;
                pk.x = pkbf(v[2 * j].x,     v[2 * j].y);
                pk.y = pkbf(v[2 * j].z,     v[2 * j].w);
                pk.z = pkbf(v[2 * j + 1].x, v[2 * j + 1].y);
                pk.w = pkbf(v[2 * j + 1].z, v[2 * j + 1].w);
                *(uint4*)(bp + 4096 + j * 1024 + lane * 16) = pk;
            }
        }
        __syncthreads();
    }
}

extern "C" void kernel_launch(void* const* d_in, const int* in_sizes, int n_in,
                              void* d_out, int out_size, void* d_ws, size_t ws_size,
                              hipStream_t stream) {
    const float* data = (const float*)d_in[0];
    const int*   idx  = (const int*)d_in[1];
    const float* Wi = (const float*)d_in[2];
    const float* bi = (const float*)d_in[3];
    const float* W1 = (const float*)d_in[4];
    const float* b1 = (const float*)d_in[5];
    const float* W2 = (const float*)d_in[6];
    const float* b2 = (const float*)d_in[7];
    const float* Wo = (const float*)d_in[8];
    const float* bo = (const float*)d_in[9];
    float* out = (float*)d_out;
    char* ws = (char*)d_ws;

    (void)hipFuncSetAttribute((const void*)main_kernel,
                              hipFuncAttributeMaxDynamicSharedMemorySize, LDS_SZ);

    // ATTRIBUTION PROBE: hyper_kernel is a pure function of d_in, so
    // launching it 3x is deterministic and output-identical.
    // dur = 3H + M;  with round-5's  H + M = 98.0 us  =>  H = (dur-98)/2.
    hipLaunchKernelGGL(hyper_kernel, dim3(M_N), dim3(512), 0, stream,
                       idx, Wi, bi, W1, b1, W2, b2, Wo, bo, ws);
    hipLaunchKernelGGL(hyper_kernel, dim3(M_N), dim3(512), 0, stream,
                       idx, Wi, bi, W1, b1, W2, b2, Wo, bo, ws);
    hipLaunchKernelGGL(hyper_kernel, dim3(M_N), dim3(512), 0, stream,
                       idx, Wi, bi, W1, b1, W2, b2, Wo, bo, ws);
    hipLaunchKernelGGL(main_kernel, dim3(256), dim3(1024), LDS_SZ, stream,
                       data, ws, out);
}

// Round 9
// 87.731 us; speedup vs baseline: 1.8366x; 1.8366x over previous
//
#include <hip/hip_runtime.h>
#include <hip/hip_bf16.h>

typedef __attribute__((ext_vector_type(8))) short bf16x8;
typedef __attribute__((ext_vector_type(4))) float f32x4;

#define B_N   16384
#define INP_N 4096
#define M_N   100
#define K_N   32
#define HID_N 32
#define OUT_W 10

// ---------------- workspace layout (bytes) ----------------
#define WS_TW1 0u         // bf16[100][32][32]   tW1[m][h][k]      204800
#define WS_TW2 204800u    // bf16[100][16][32]   tW2[m][o(pad)][k-slot] 102400
#define WS_TB1 307200u    // f32 [100][32]       tb1               12800
#define WS_TB2 320000u    // f32 [100][16]       tb2               6400
#define WS_COL 326400u    // u16 [100][32]       idx cols packed   6400
#define WS_H2  332800u    // f32 [100][128]      h2 activations    51200
// total 384000 B

// ---------------- kernel-2 LDS layout (bytes) ----------------
#define ROWB   8208                  // bf16 row: 8192 B data + 16 B pad (4-bank rotate/row)
#define BUFB   (16 * ROWB)           // 131328: ONE 16-row tile buffer
#define REDOFF BUFB                  // per-wave out partials
#define REDSTR 656                   // 164 dwords (16B aligned, rotates 4 banks/wave)
#define COLOFF (REDOFF + 16 * REDSTR)   // 141824: u16[100][32] col table
#define TB1OFF (COLOFF + 6400)          // 148224: f32[100][32] tb1
#define TB2OFF (TB1OFF + 12800)         // 161024: f32[10] summed tb2
#define LDS_SZ (TB2OFF + 64)            // 161088  (<= 163840)

__device__ __forceinline__ unsigned int pkbf(float a, float b) {
    __hip_bfloat162 h2 = __float22bfloat162_rn(make_float2(a, b));
    unsigned int r;
    __builtin_memcpy(&r, &h2, 4);
    return r;
}

// =====================================================================
// Kernel 1a: hypernet TRUNK (idx, h0 -> h1 -> h2 -> ws).  100 x 256.
// Arithmetic identical to the fused version's trunk phases.
// =====================================================================
__global__ __launch_bounds__(256) void hyperT_kernel(
    const int* __restrict__ idx,
    const float* __restrict__ Wi, const float* __restrict__ bi,
    const float* __restrict__ W1, const float* __restrict__ b1,
    const float* __restrict__ W2, const float* __restrict__ b2,
    char* __restrict__ ws)
{
    __shared__ int   s_idx[K_N];
    __shared__ float s_h0[64];
    __shared__ float s_h1[256];
    const int m = blockIdx.x;
    const int t = threadIdx.x;

    __hip_bfloat16* tW2bf = (__hip_bfloat16*)(ws + WS_TW2);
    unsigned short* colb = (unsigned short*)(ws + WS_COL);
    float* h2p = (float*)(ws + WS_H2);

    if (t < K_N) {
        int c = idx[m * K_N + t];
        s_idx[t] = c;
        colb[m * K_N + t] = (unsigned short)c;
    }
    // zero padded tW2 rows o'=10..15 (slots 320..511; disjoint from head stores)
    if (t < 192) tW2bf[m * 512 + 320 + t] = __float2bfloat16(0.f);
    __syncthreads();

    if (t < 64) {   // h0 = relu(sum over UNIQUE sorted idx cols + bi)
        float s = bi[t];
        const float* wr = Wi + t * INP_N;
        int prev = -1;
        for (int k = 0; k < K_N; ++k) {
            int c = s_idx[k];
            if (c != prev) s += wr[c];
            prev = c;
        }
        s_h0[t] = fmaxf(s, 0.f);
    }
    __syncthreads();

    {   // h1 = relu(W1 h0 + b1), 256 outputs
        float4 a = {0.f, 0.f, 0.f, 0.f};
        const float4* wr = (const float4*)(W1 + t * 64);
        const float4* h0v = (const float4*)s_h0;
        #pragma unroll
        for (int i = 0; i < 16; ++i) {
            float4 w4 = wr[i], a4 = h0v[i];
            a.x += w4.x * a4.x; a.y += w4.y * a4.y;
            a.z += w4.z * a4.z; a.w += w4.w * a4.w;
        }
        s_h1[t] = fmaxf(b1[t] + (a.x + a.y) + (a.z + a.w), 0.f);
    }
    __syncthreads();

    if (t < 128) {  // h2 = relu(W2 h1 + b2) -> ws
        float4 a = {0.f, 0.f, 0.f, 0.f};
        const float4* wr = (const float4*)(W2 + t * 256);
        const float4* h1v = (const float4*)s_h1;
        #pragma unroll
        for (int i = 0; i < 64; ++i) {
            float4 w4 = wr[i], a4 = h1v[i];
            a.x += w4.x * a4.x; a.y += w4.y * a4.y;
            a.z += w4.z * a4.z; a.w += w4.w * a4.w;
        }
        h2p[m * 128 + t] = fmaxf(b2[t] + (a.x + a.y) + (a.z + a.w), 0.f);
    }
}

// =====================================================================
// Kernel 1b: hypernet HEAD.  grid (100, 6) x 256: one output o per
// thread (bit-identical dot arithmetic to the fused version), routed
// to tW1/tb1/tW2(k-slot-permuted)/tb2.
// =====================================================================
__global__ __launch_bounds__(256) void hyperH_kernel(
    const float* __restrict__ Wo, const float* __restrict__ bo,
    char* __restrict__ ws)
{
    __shared__ float h2s[128];
    const int m = blockIdx.x;
    const int seg = blockIdx.y;
    const int t = threadIdx.x;

    __hip_bfloat16* tW1bf = (__hip_bfloat16*)(ws + WS_TW1);
    __hip_bfloat16* tW2bf = (__hip_bfloat16*)(ws + WS_TW2);
    float* tb1f = (float*)(ws + WS_TB1);
    float* tb2f = (float*)(ws + WS_TB2);
    const float* h2p = (const float*)(ws + WS_H2);

    if (t < 128) h2s[t] = h2p[m * 128 + t];
    __syncthreads();

    const int o = seg * 256 + t;
    if (o < 1386) {
        float4 a = {0.f, 0.f, 0.f, 0.f};
        const float4* wr = (const float4*)(Wo + o * 128);
        const float4* h2v = (const float4*)h2s;
        #pragma unroll
        for (int i = 0; i < 32; ++i) {
            float4 w4 = wr[i], a4 = h2v[i];
            a.x += w4.x * a4.x; a.y += w4.y * a4.y;
            a.z += w4.z * a4.z; a.w += w4.w * a4.w;
        }
        float s = bo[o] + (a.x + a.y) + (a.z + a.w);
        if (o < 1024) {                     // tW1[m][h][k]
            tW1bf[m * 1024 + o] = __float2bfloat16(s);
        } else if (o < 1056) {
            tb1f[m * 32 + (o - 1024)] = s;
        } else if (o < 1376) {              // tW2 k-slot permuted
            int i2 = o - 1056;
            int oo = i2 >> 5, h = i2 & 31;
            int sl = (((h & 15) >> 2) << 3) + (h & 3) + ((h >> 4) << 2);
            tW2bf[m * 512 + oo * 32 + sl] = __float2bfloat16(s);
        } else {
            tb2f[m * 16 + (o - 1376)] = s;
        }
    }
}

// =====================================================================
// Kernel 2: main loop -- byte-exact round-5 version (best, M = 66.4us).
// =====================================================================
__global__ __launch_bounds__(1024) void main_kernel(
    const float* __restrict__ data,
    const char* __restrict__ ws,
    float* __restrict__ out)
{
    extern __shared__ char smem[];
    const int tid  = threadIdx.x;
    const int lane = tid & 63;
    const int wave = tid >> 6;       // 0..15 ; wave w stages row w of each tile
    const int kg   = lane >> 4;      // 0..3  (MFMA k-group)
    const int ln15 = lane & 15;

    unsigned int* s_col = (unsigned int*)(smem + COLOFF);
    float* s_tb1 = (float*)(smem + TB1OFF);
    float* tb2s  = (float*)(smem + TB2OFF);

    // ---- small tables -> LDS ----
    {
        const unsigned int* colg = (const unsigned int*)(ws + WS_COL);
        for (int i = tid; i < 1600; i += 1024) s_col[i] = colg[i];
        const float* tb1g = (const float*)(ws + WS_TB1);
        for (int i = tid; i < 3200; i += 1024) s_tb1[i] = tb1g[i];
        if (tid < OUT_W) {
            const float* tb2f = (const float*)(ws + WS_TB2);
            float s = 0.f;
            for (int mm = 0; mm < M_N; ++mm) s += tb2f[mm * 16 + tid];
            tb2s[tid] = s;
        }
    }

    const int row0 = blockIdx.x * 64;         // 4 tiles x 16 rows
    const int mlo = (wave * M_N) >> 4;
    const int mhi = ((wave + 1) * M_N) >> 4;

    float4 v[8];                              // staging regs (one half-row)

    // ---- prologue: stage tile0 fully (both halves) ----
    {
        const float* rp = data + (size_t)(row0 + wave) * INP_N;
        char* bp = smem + wave * ROWB;
        #pragma unroll
        for (int half = 0; half < 2; ++half) {
            #pragma unroll
            for (int j = 0; j < 4; ++j) {
                v[2 * j]     = *(const float4*)(rp + half * 2048 + j * 512 + lane * 8);
                v[2 * j + 1] = *(const float4*)(rp + half * 2048 + j * 512 + lane * 8 + 4);
            }
            #pragma unroll
            for (int j = 0; j < 4; ++j) {
                uint4 pk;
                pk.x = pkbf(v[2 * j].x,     v[2 * j].y);
                pk.y = pkbf(v[2 * j].z,     v[2 * j].w);
                pk.z = pkbf(v[2 * j + 1].x, v[2 * j + 1].y);
                pk.w = pkbf(v[2 * j + 1].z, v[2 * j + 1].w);
                *(uint4*)(bp + half * 4096 + j * 1024 + lane * 16) = pk;
            }
        }
    }
    __syncthreads();

    for (int ti = 0; ti < 4; ++ti) {
        // early-issue next tile half0 (HBM hides under m-loop)
        if (ti < 3) {
            const float* rp = data + (size_t)(row0 + (ti + 1) * 16 + wave) * INP_N;
            #pragma unroll
            for (int j = 0; j < 4; ++j) {
                v[2 * j]     = *(const float4*)(rp + j * 512 + lane * 8);
                v[2 * j + 1] = *(const float4*)(rp + j * 512 + lane * 8 + 4);
            }
        }

        // ---- m-loop on current tile (16 real rows) ----
        const char* gbase = smem + ln15 * ROWB;
        f32x4 acc = {0.f, 0.f, 0.f, 0.f};

        // prefetch first column word
        uint4 cw = *(const uint4*)((const char*)s_col + mlo * 64 + kg * 16);

        for (int m = mlo; m < mhi; ++m) {
            // prefetch next m's column word (dep chain head)
            const int mn = (m + 1 < M_N) ? (m + 1) : m;
            const uint4 cwn = *(const uint4*)((const char*)s_col + mn * 64 + kg * 16);

            // B-frag (md): md[b=ln15][k=kg*8+j] gathered from staged bf16 row
            unsigned short u0 = *(const unsigned short*)(gbase + 2 * (cw.x & 0xFFFFu));
            unsigned short u1 = *(const unsigned short*)(gbase + 2 * (cw.x >> 16));
            unsigned short u2 = *(const unsigned short*)(gbase + 2 * (cw.y & 0xFFFFu));
            unsigned short u3 = *(const unsigned short*)(gbase + 2 * (cw.y >> 16));
            unsigned short u4 = *(const unsigned short*)(gbase + 2 * (cw.z & 0xFFFFu));
            unsigned short u5 = *(const unsigned short*)(gbase + 2 * (cw.z >> 16));
            unsigned short u6 = *(const unsigned short*)(gbase + 2 * (cw.w & 0xFFFFu));
            unsigned short u7 = *(const unsigned short*)(gbase + 2 * (cw.w >> 16));
            union { unsigned int ui[4]; bf16x8 v8; } af;
            af.ui[0] = (unsigned int)u0 | ((unsigned int)u1 << 16);
            af.ui[1] = (unsigned int)u2 | ((unsigned int)u3 << 16);
            af.ui[2] = (unsigned int)u4 | ((unsigned int)u5 << 16);
            af.ui[3] = (unsigned int)u6 | ((unsigned int)u7 << 16);

            // A-frags: tW1 rows h=ln15 / h=ln15+16; tW2 rows o=ln15 (slot-permuted)
            const bf16x8 w1a = *(const bf16x8*)(ws + WS_TW1 + m * 2048 + ln15 * 64 + kg * 16);
            const bf16x8 w1b = *(const bf16x8*)(ws + WS_TW1 + m * 2048 + 1024 + ln15 * 64 + kg * 16);
            const bf16x8 w2f = *(const bf16x8*)(ws + WS_TW2 + m * 1024 + ln15 * 64 + kg * 16);
            const float4 bq0 = *(const float4*)(s_tb1 + m * 32 + kg * 4);
            const float4 bq1 = *(const float4*)(s_tb1 + m * 32 + 16 + kg * 4);

            // MFMA1: C[h][b] = W1 x md  (bias tb1[h] as C-in; h = kg*4+r)
            f32x4 c0 = {bq0.x, bq0.y, bq0.z, bq0.w};
            f32x4 c1 = {bq1.x, bq1.y, bq1.z, bq1.w};
            c0 = __builtin_amdgcn_mfma_f32_16x16x32_bf16(w1a, af.v8, c0, 0, 0, 0);
            c1 = __builtin_amdgcn_mfma_f32_16x16x32_bf16(w1b, af.v8, c1, 0, 0, 0);

            // relu + pack: lane(b,kg) holds exactly its MFMA2 B-frag k-slots
            // (k=kg*8+j <-> h = 4kg + (j&3) + (j>=4 ? 16 : 0), matching tW2 store)
            #pragma unroll
            for (int r = 0; r < 4; ++r) { c0[r] = fmaxf(c0[r], 0.f); c1[r] = fmaxf(c1[r], 0.f); }
            union { unsigned int ui[4]; bf16x8 v8; } bfr;
            bfr.ui[0] = pkbf(c0[0], c0[1]);
            bfr.ui[1] = pkbf(c0[2], c0[3]);
            bfr.ui[2] = pkbf(c1[0], c1[1]);
            bfr.ui[3] = pkbf(c1[2], c1[3]);

            // MFMA2: acc[o][b] += tW2[o][.] x th[.][b]
            acc = __builtin_amdgcn_mfma_f32_16x16x32_bf16(w2f, bfr.v8, acc, 0, 0, 0);

            cw = cwn;
        }

        // per-wave partials: acc row o=kg*4+r, col b=ln15 (all 16 b real)
        {
            float* red = (float*)(smem + REDOFF + wave * REDSTR);
            #pragma unroll
            for (int r = 0; r < 4; ++r) {
                int o = kg * 4 + r;
                if (o < OUT_W) red[o * 16 + ln15] = acc[r];
            }
        }
        __syncthreads();

        // reduce 16 waves + tb2 + mean (160 threads) -- overlaps with the
        // register->LDS conversion below on the other threads
        if (tid < 160) {
            const int o = tid >> 4, b = tid & 15;
            float s = tb2s[o];
            #pragma unroll
            for (int w = 0; w < 16; ++w)
                s += *(const float*)(smem + REDOFF + w * REDSTR + tid * 4);
            out[(size_t)(row0 + ti * 16 + b) * OUT_W + o] = s * 0.01f;
        }

        // write phase: half0 from regs, then load+write half1
        if (ti < 3) {
            char* bp = smem + wave * ROWB;
            #pragma unroll
            for (int j = 0; j < 4; ++j) {
                uint4 pk;
                pk.x = pkbf(v[2 * j].x,     v[2 * j].y);
                pk.y = pkbf(v[2 * j].z,     v[2 * j].w);
                pk.z = pkbf(v[2 * j + 1].x, v[2 * j + 1].y);
                pk.w = pkbf(v[2 * j + 1].z, v[2 * j + 1].w);
                *(uint4*)(bp + j * 1024 + lane * 16) = pk;
            }
            const float* rp = data + (size_t)(row0 + (ti + 1) * 16 + wave) * INP_N + 2048;
            #pragma unroll
            for (int j = 0; j < 4; ++j) {
                v[2 * j]     = *(const float4*)(rp + j * 512 + lane * 8);
                v[2 * j + 1] = *(const float4*)(rp + j * 512 + lane * 8 + 4);
            }
            #pragma unroll
            for (int j = 0; j < 4; ++j) {
                uint4 pk;
                pk.x = pkbf(v[2 * j].x,     v[2 * j].y);
                pk.y = pkbf(v[2 * j].z,     v[2 * j].w);
                pk.z = pkbf(v[2 * j + 1].x, v[2 * j + 1].y);
                pk.w = pkbf(v[2 * j + 1].z, v[2 * j + 1].w);
                *(uint4*)(bp + 4096 + j * 1024 + lane * 16) = pk;
            }
        }
        __syncthreads();
    }
}

extern "C" void kernel_launch(void* const* d_in, const int* in_sizes, int n_in,
                              void* d_out, int out_size, void* d_ws, size_t ws_size,
                              hipStream_t stream) {
    const float* data = (const float*)d_in[0];
    const int*   idx  = (const int*)d_in[1];
    const float* Wi = (const float*)d_in[2];
    const float* bi = (const float*)d_in[3];
    const float* W1 = (const float*)d_in[4];
    const float* b1 = (const float*)d_in[5];
    const float* W2 = (const float*)d_in[6];
    const float* b2 = (const float*)d_in[7];
    const float* Wo = (const float*)d_in[8];
    const float* bo = (const float*)d_in[9];
    float* out = (float*)d_out;
    char* ws = (char*)d_ws;

    (void)hipFuncSetAttribute((const void*)main_kernel,
                              hipFuncAttributeMaxDynamicSharedMemorySize, LDS_SZ);

    hipLaunchKernelGGL(hyperT_kernel, dim3(M_N), dim3(256), 0, stream,
                       idx, Wi, bi, W1, b1, W2, b2, ws);
    hipLaunchKernelGGL(hyperH_kernel, dim3(M_N, 6), dim3(256), 0, stream,
                       Wo, bo, ws);
    hipLaunchKernelGGL(main_kernel, dim3(256), dim3(1024), LDS_SZ, stream,
                       data, ws, out);
}